// Round 1
// baseline (99.682 us; speedup 1.0000x reference)
//
#include <hip/hip_runtime.h>
#include <math.h>

#define NIMG 24        // B*C = 8*3
#define H    256
#define W    256
#define NBLK (NIMG * W)
#define BIGF 1.0e6f

// ---------------------------------------------------------------------------
// Pass 1: per-row 1-D EDT (both polarities), written TRANSPOSED per image:
//   g[img][j][row]  (column-contiguous) so pass 2 reads columns coalesced.
// Replicates reference fp32 semantics exactly:
//   last = index of last zero to the left (or -BIG), nxt = first zero to the
//   right (or +BIG); g = min(j - last, nxt - j, BIG); store g*g.
// ---------------------------------------------------------------------------
__global__ void edt_rows_kernel(const int* __restrict__ tgt,
                                float* __restrict__ gp2,   // polarity: t == 0
                                float* __restrict__ gn2,   // polarity: t != 0
                                int* __restrict__ flags) {
    const int img = blockIdx.x;    // 0..23
    const int row = threadIdx.x;   // 0..255
    const int* t = tgt + (size_t)img * (H * W) + (size_t)row * W;
    float* gp = gp2 + (size_t)img * (H * W);
    float* gn = gn2 + (size_t)img * (H * W);

    __shared__ int anynz;
    if (row == 0) anynz = 0;
    __syncthreads();

    // backward scan: store (nxt - j) as temp
    float nxtP = BIGF, nxtN = BIGF;   // "index" of next zero; BIGF == none
    for (int j = W - 1; j >= 0; --j) {
        int tv = t[j];
        if (tv == 0) nxtP = (float)j; else nxtN = (float)j;
        gp[j * H + row] = nxtP - (float)j;
        gn[j * H + row] = nxtN - (float)j;
    }
    // forward scan: combine with (j - last), cap at BIG, square
    float lastP = -BIGF, lastN = -BIGF;
    int nz = 0;
    for (int j = 0; j < W; ++j) {
        int tv = t[j];
        if (tv == 0) { lastP = (float)j; } else { lastN = (float)j; nz = 1; }
        float gPv = fminf(fminf((float)j - lastP, gp[j * H + row]), BIGF);
        float gNv = fminf(fminf((float)j - lastN, gn[j * H + row]), BIGF);
        gp[j * H + row] = gPv * gPv;
        gn[j * H + row] = gNv * gNv;
    }
    if (nz) atomicOr(&anynz, 1);
    __syncthreads();
    if (row == 0) flags[img] = anynz;   // 0 => mask.sum()==0 => dmap forced 0
}

// ---------------------------------------------------------------------------
// Pass 2: one block per (img, column j); thread i computes
//   D2[i,j] = min_k g2[k,j] + (i-k)^2   for both polarities,
// then term = sigmoid(pred[img,i,j]) * (sqrt(pos2) - sqrt(neg2)).
// Deterministic block reduction into per-block double partial.
// ---------------------------------------------------------------------------
__global__ void edt_cols_kernel(const float* __restrict__ gp2,
                                const float* __restrict__ gn2,
                                const float* __restrict__ pred,
                                const int* __restrict__ flags,
                                double* __restrict__ partials) {
    const int blk = blockIdx.x;        // img*W + j
    const int img = blk >> 8;
    const int j   = blk & (W - 1);
    const int i   = threadIdx.x;       // output row

    __shared__ float sp[H];
    __shared__ float sn[H];
    const size_t base = (size_t)img * (H * W) + (size_t)j * H;
    sp[i] = gp2[base + i];
    sn[i] = gn2[base + i];
    __syncthreads();

    const float fi = (float)i;
    float dp = 3.0e38f, dn = 3.0e38f;
#pragma unroll 16
    for (int k = 0; k < H; ++k) {
        float d = fi - (float)k;
        float s = d * d;
        dp = fminf(dp, sp[k] + s);
        dn = fminf(dn, sn[k] + s);
    }

    float dmap = sqrtf(dp) - sqrtf(dn);
    if (flags[img] == 0) dmap = 0.0f;
    float p = pred[(size_t)img * (H * W) + (size_t)i * W + j];
    float sig = 1.0f / (1.0f + expf(-p));
    double term = (double)sig * (double)dmap;

    __shared__ double sred[H];
    sred[i] = term;
    __syncthreads();
    for (int off = H / 2; off > 0; off >>= 1) {
        if (i < off) sred[i] += sred[i + off];
        __syncthreads();
    }
    if (i == 0) partials[blk] = sred[0];
}

// ---------------------------------------------------------------------------
// Finalize: deterministic sum of 6144 partials -> mean -> fp32
// ---------------------------------------------------------------------------
__global__ void finalize_kernel(const double* __restrict__ partials,
                                float* __restrict__ out) {
    const int tid = threadIdx.x;
    __shared__ double sred[256];
    double s = 0.0;
    for (int p = tid; p < NBLK; p += 256) s += partials[p];
    sred[tid] = s;
    __syncthreads();
    for (int off = 128; off > 0; off >>= 1) {
        if (tid < off) sred[tid] += sred[tid + off];
        __syncthreads();
    }
    if (tid == 0) out[0] = (float)(sred[0] / (double)(NIMG * H * W));
}

extern "C" void kernel_launch(void* const* d_in, const int* in_sizes, int n_in,
                              void* d_out, int out_size, void* d_ws, size_t ws_size,
                              hipStream_t stream) {
    const float* pred = (const float*)d_in[0];
    const int*   tgt  = (const int*)d_in[1];
    float* out = (float*)d_out;

    char* ws = (char*)d_ws;
    const size_t gbytes = (size_t)NIMG * H * W * sizeof(float);   // 6,291,456 B
    float*  gp2      = (float*)(ws);
    float*  gn2      = (float*)(ws + gbytes);
    double* partials = (double*)(ws + 2 * gbytes);                // 6144 * 8 B
    int*    flags    = (int*)(ws + 2 * gbytes + (size_t)NBLK * sizeof(double));

    edt_rows_kernel<<<NIMG, H, 0, stream>>>(tgt, gp2, gn2, flags);
    edt_cols_kernel<<<NBLK, H, 0, stream>>>(gp2, gn2, pred, flags, partials);
    finalize_kernel<<<1, 256, 0, stream>>>(partials, out);
}